// Round 1
// baseline (85.412 us; speedup 1.0000x reference)
//
#include <hip/hip_runtime.h>
#include <stdint.h>

#define N_ANCH 65648
#define NCHUNK 17          // ceil(65648/4096)
#define CHUNK  4096
#define CAP    4096        // candidate capacity per batch
#define KBASE  0xBE800000u // sortable key of score 0.25 (all fg scores >= 1/3)
#define NBATCH 32
#define TOPK   100

struct Ptrs { const float* cls[8]; const float* reg[8]; };

__constant__ int   c_off[9] = {0,25281,50562,56803,63044,64565,64926,65287,65648};
__constant__ int   c_sz[8]  = {159,159,79,79,39,19,19,19};
__constant__ float c_st[8]  = {4.f,4.f,8.f,8.f,16.f,32.f,32.f,32.f};
__constant__ float c_rf[8]  = {27.5f,35.5f,55.5f,71.5f,111.5f,191.5f,255.5f,319.5f};

// sortable key for the masked score of anchor n in batch b; 0 if background
__device__ inline uint32_t anchor_key(const Ptrs& p, int b, int n) {
  int k = 0;
#pragma unroll
  for (int q = 1; q < 8; ++q) if (n >= c_off[q]) k = q;
  int local = n - c_off[k];
  int hw = c_sz[k] * c_sz[k];
  const float* c = p.cls[k] + (size_t)(b * 3) * hw + local;
  float l0 = c[0], l1 = c[(size_t)hw], l2 = c[(size_t)2 * hw];
  float m = l0; int cl = 0;
  if (l1 > m) { m = l1; cl = 1; }
  if (l2 > m) { m = l2; cl = 2; }
  if (cl == 0) return 0u;                 // background -> masked score -1, never in top range
  // max softmax prob = exp(0)/sum = 1/sum (same fp sequence as numpy ref)
  float s = 1.0f / (expf(l0 - m) + expf(l1 - m) + expf(l2 - m));
  return __float_as_uint(s) | 0x80000000u; // positive float -> monotonic uint
}

__global__ void k_hist(Ptrs p, uint32_t* hist) {
  int bid = blockIdx.x;
  int b = bid / NCHUNK, chunk = bid % NCHUNK;
  __shared__ uint32_t lh[256];
  lh[threadIdx.x] = 0;
  __syncthreads();
  int n0 = chunk * CHUNK;
  for (int t = threadIdx.x; t < CHUNK; t += 256) {
    int n = n0 + t;
    if (n < N_ANCH) {
      uint32_t key = anchor_key(p, b, n);
      if (key >= KBASE) atomicAdd(&lh[(key - KBASE) >> 16], 1u);
    }
  }
  __syncthreads();
  uint32_t v = lh[threadIdx.x];
  if (v) atomicAdd(&hist[b * 256 + threadIdx.x], v);
}

__global__ void k_collect(Ptrs p, const uint32_t* hist, uint32_t* counter,
                          unsigned long long* cand) {
  int bid = blockIdx.x;
  int b = bid / NCHUNK, chunk = bid % NCHUNK;
  __shared__ uint32_t lh[256];
  __shared__ uint32_t s_thr;
  lh[threadIdx.x] = hist[b * 256 + threadIdx.x];
  __syncthreads();
  if (threadIdx.x == 0) {
    uint32_t cum = 0, thv = KBASE;
    for (int t = 255; t >= 0; --t) {
      cum += lh[t];
      if (cum >= TOPK) { thv = KBASE + ((uint32_t)t << 16); break; }
    }
    s_thr = thv;
  }
  __syncthreads();
  uint32_t th = s_thr;
  int n0 = chunk * CHUNK;
  for (int t = threadIdx.x; t < CHUNK; t += 256) {
    int n = n0 + t;
    if (n < N_ANCH) {
      uint32_t key = anchor_key(p, b, n);
      if (key >= th) {
        uint32_t pos = atomicAdd(&counter[b], 1u);
        if (pos < CAP)
          cand[(size_t)b * CAP + pos] =
              ((unsigned long long)key << 32) | (uint32_t)(~(uint32_t)n);
      }
    }
  }
}

__global__ void k_final(Ptrs p, const uint32_t* counter,
                        const unsigned long long* cand, float* out) {
  int b = blockIdx.x;
  __shared__ unsigned long long s[CAP];
  __shared__ float bx1[TOPK], by1[TOPK], bx2[TOPK], by2[TOPK], area[TOPK], sc[TOPK];
  __shared__ int cls_s[TOPK];
  __shared__ int keep[TOPK];

  int c = (int)min(counter[b], (uint32_t)CAP);
  int P = 128;
  while (P < c) P <<= 1;
  for (int i = threadIdx.x; i < P; i += 256)
    s[i] = (i < c) ? cand[(size_t)b * CAP + i] : 0ull;
  __syncthreads();

  // bitonic sort ascending; rank r = s[P-1-r]
  for (int k = 2; k <= P; k <<= 1) {
    for (int j = k >> 1; j > 0; j >>= 1) {
      for (int i = threadIdx.x; i < P; i += 256) {
        int ixj = i ^ j;
        if (ixj > i) {
          unsigned long long a = s[i], bb = s[ixj];
          bool up = ((i & k) == 0);
          if ((a > bb) == up) { s[i] = bb; s[ixj] = a; }
        }
      }
      __syncthreads();
    }
  }

  int r = threadIdx.x;
  if (r < TOPK) {
    unsigned long long pk = s[P - 1 - r];
    if (pk == 0ull) {
      sc[r] = -1.f; cls_s[r] = 0; keep[r] = 0;
      bx1[r] = by1[r] = bx2[r] = by2[r] = 0.f; area[r] = 1.f;
    } else {
      uint32_t key = (uint32_t)(pk >> 32);
      int n = (int)(~(uint32_t)pk);
      float score = __uint_as_float(key & 0x7FFFFFFFu);
      int k2 = 0;
#pragma unroll
      for (int q = 1; q < 8; ++q) if (n >= c_off[q]) k2 = q;
      int local = n - c_off[k2];
      int w = c_sz[k2], hw = w * w;
      int i2 = local / w, j2 = local % w;
      const float* cp = p.cls[k2] + (size_t)(b * 3) * hw + local;
      float l0 = cp[0], l1 = cp[(size_t)hw], l2 = cp[(size_t)2 * hw];
      float m = l0; int cl = 0;
      if (l1 > m) { m = l1; cl = 1; }
      if (l2 > m) { m = l2; cl = 2; }
      const float* rp = p.reg[k2] + (size_t)(b * 4) * hw + local;
      float r0 = rp[0], r1 = rp[(size_t)hw], r2 = rp[(size_t)2 * hw], r3 = rp[(size_t)3 * hw];
      float st = c_st[k2], rf = c_rf[k2];
      float cx = (float)j2 * st + st * 0.5f;
      float cy = (float)i2 * st + st * 0.5f;
      float x1 = cx - r0 * rf, y1 = cy - r1 * rf;
      float x2 = cx + r2 * rf, y2 = cy + r3 * rf;
      sc[r] = score; cls_s[r] = cl;
      bx1[r] = x1; by1[r] = y1; bx2[r] = x2; by2[r] = y2;
      area[r] = (x2 - x1 + 1.0f) * (y2 - y1 + 1.0f);
      keep[r] = (score >= 0.35f && cl > 0) ? 1 : 0;
    }
  }
  __syncthreads();

  // greedy NMS, 100 sequential steps
  for (int i = 0; i < TOPK; ++i) {
    if (r < TOPK && r > i && keep[i] && keep[r]) {
      float xmin = fmaxf(bx1[i], bx1[r]);
      float ymin = fmaxf(by1[i], by1[r]);
      float xmax = fminf(bx2[i], bx2[r]);
      float ymax = fminf(by2[i], by2[r]);
      float iw = fmaxf(xmax - xmin, 0.f);
      float ih = fmaxf(ymax - ymin, 0.f);
      float inter = iw * ih;
      float iou = inter / (area[i] + area[r] - inter);
      if (iou > 0.5f) keep[r] = 0;
    }
    __syncthreads();
  }

  if (r < TOPK) {
    int o = b * TOPK + r;
    bool kp = keep[r] != 0;
    out[o] = kp ? sc[r] : 0.f;                                  // scores
    out[NBATCH * TOPK + o] = kp ? (float)cls_s[r] : 0.f;        // classes
    float* ob = out + 2 * NBATCH * TOPK + (size_t)o * 4;        // boxes
    ob[0] = kp ? bx1[r] : 0.f;
    ob[1] = kp ? by1[r] : 0.f;
    ob[2] = kp ? bx2[r] : 0.f;
    ob[3] = kp ? by2[r] : 0.f;
    out[6 * NBATCH * TOPK + o] = kp ? 1.f : 0.f;                // keep
  }
}

extern "C" void kernel_launch(void* const* d_in, const int* in_sizes, int n_in,
                              void* d_out, int out_size, void* d_ws, size_t ws_size,
                              hipStream_t stream) {
  Ptrs p;
  // setup_inputs() dict order is INTERLEAVED: cls0, reg0, cls1, reg1, ...
  for (int i = 0; i < 8; ++i) {
    p.cls[i] = (const float*)d_in[2 * i];
    p.reg[i] = (const float*)d_in[2 * i + 1];
  }
  uint32_t* hist    = (uint32_t*)d_ws;                          // 32*256*4 = 32768 B
  uint32_t* counter = (uint32_t*)((char*)d_ws + 32768);         // 128 B
  unsigned long long* cand =
      (unsigned long long*)((char*)d_ws + 32896);               // 32*4096*8 = 1 MiB
  float* out = (float*)d_out;

  hipMemsetAsync(d_ws, 0, 32896, stream);
  k_hist<<<NBATCH * NCHUNK, 256, 0, stream>>>(p, hist);
  k_collect<<<NBATCH * NCHUNK, 256, 0, stream>>>(p, hist, counter, cand);
  k_final<<<NBATCH, 256, 0, stream>>>(p, counter, cand, out);
}